// Round 12
// baseline (528.619 us; speedup 1.0000x reference)
//
#include <hip/hip_runtime.h>
#include <hip/hip_bf16.h>
#include <cstdint>
#include <cmath>

#define B_DIM 8192
#define H_DIM 1024
#define K_DIM 2048   // 2H
#define N_DIM 10240  // 10H

typedef __bf16 bf16x8 __attribute__((ext_vector_type(8)));
typedef float  f32x4  __attribute__((ext_vector_type(4)));

static __device__ __forceinline__ float sigmoid_f(float z) {
    return 1.0f / (1.0f + __expf(-z));
}
static __device__ __forceinline__ float tanh_f(float z) {
    return 1.0f - 2.0f / (1.0f + __expf(2.0f * z));
}
static __device__ __forceinline__ float softplus_f(float z) {
    return fmaxf(z, 0.0f) + log1pf(__expf(-fabsf(z)));
}

static __device__ __forceinline__ void store_bf16x4(__bf16* p, float4 v) {
    alignas(8) __bf16 t[4] = {(__bf16)v.x, (__bf16)v.y, (__bf16)v.z, (__bf16)v.w};
    *reinterpret_cast<uint2*>(p) = *reinterpret_cast<const uint2*>(t);
}

static __device__ __forceinline__ void gload_lds16(const void* g, void* l) {
    auto* gp = reinterpret_cast<__attribute__((address_space(1))) unsigned int*>(
        reinterpret_cast<uintptr_t>(g));
    auto* lp = reinterpret_cast<__attribute__((address_space(3))) unsigned int*>(
        reinterpret_cast<uintptr_t>(l));
    __builtin_amdgcn_global_load_lds(gp, lp, 16, 0, 0);
}

// ---------------- pack kernels (unchanged) ----------------

__global__ void pack_xh_kernel(const float* __restrict__ x, const float* __restrict__ h,
                               __bf16* __restrict__ xh) {
    const int64_t total = (int64_t)B_DIM * K_DIM / 4;
    for (int64_t i = (int64_t)blockIdx.x * blockDim.x + threadIdx.x; i < total;
         i += (int64_t)gridDim.x * blockDim.x) {
        int64_t e = i << 2;
        int64_t b = e >> 11;
        int     c = (int)(e & 2047);
        const float* src = (c < H_DIM) ? (x + b * H_DIM + c) : (h + b * H_DIM + (c - H_DIM));
        float4 v = *reinterpret_cast<const float4*>(src);
        store_bf16x4(xh + e, v);
    }
}

__global__ void pack_W_kernel(const float* __restrict__ w0, const float* __restrict__ w1,
                              const float* __restrict__ w2, const float* __restrict__ w3,
                              const float* __restrict__ w4, const float* __restrict__ w5,
                              const float* __restrict__ wd, __bf16* __restrict__ dst) {
    const int64_t total = (int64_t)N_DIM * K_DIM / 4;
    for (int64_t i = (int64_t)blockIdx.x * blockDim.x + threadIdx.x; i < total;
         i += (int64_t)gridDim.x * blockDim.x) {
        int64_t e   = i << 2;
        int     blk = (int)(e >> 21);
        const float* src;
        int64_t off;
        if (blk < 6) {
            src = (blk == 0) ? w0 : (blk == 1) ? w1 : (blk == 2) ? w2
                : (blk == 3) ? w3 : (blk == 4) ? w4 : w5;
            off = e - ((int64_t)blk << 21);
        } else {
            src = wd;
            off = e - ((int64_t)6 << 21);
        }
        float4 v = *reinterpret_cast<const float4*>(src + off);
        store_bf16x4(dst + e, v);
    }
}

__global__ void pack_bias_kernel(const float* __restrict__ b0, const float* __restrict__ b1,
                                 const float* __restrict__ b2, const float* __restrict__ b3,
                                 const float* __restrict__ b4, const float* __restrict__ b5,
                                 const float* __restrict__ bd, float* __restrict__ dst) {
    int i = blockIdx.x * blockDim.x + threadIdx.x;
    if (i >= N_DIM) return;
    int blk = i >> 10;
    float v;
    if (blk < 6) {
        const float* s = (blk == 0) ? b0 : (blk == 1) ? b1 : (blk == 2) ? b2
                       : (blk == 3) ? b3 : (blk == 4) ? b4 : b5;
        v = s[i - (blk << 10)];
    } else {
        v = bd[i - (6 << 10)];
    }
    dst[i] = v;
}

// ---------------- GEMM: 128x128, BK=32 DOUBLE-BUFFERED, 4 blocks/CU preserved ----------------
// r6-r11: perf tracks blocks/CU (1->680, 2->506, 4->457us); 5 blocks is register-infeasible
// (64 acc regs irreducible). Remaining lever: remove the per-K-step serial chain
// (barrier -> vmcnt(0) drain -> ds_read -> MFMA) WITHOUT losing occupancy. All prior dbuf
// attempts (m99/m100/m132) were confounded by LDS growth; BK=32 dbuf keeps 32KB total:
//   2 bufs x (As[128][32] + Bs[128][32]) = 32KB -> still 4 blocks/CU.
// Per step: stage buf^1 (k+1) FIRST, then compute buf -> the forced vmcnt(0) at the barrier
// drains loads issued ~300cy earlier instead of stalling cold. 64 steps, 1 barrier each.
// Swizzle (64B rows, 4 chunks): chunk c of row r at c^((r>>1)&3) -> 2 lanes/bank (free).
// Map/epilogue/packs/combine unchanged from r11.

#define MFMA_(Af, Bf, C) __builtin_amdgcn_mfma_f32_16x16x32_bf16(Af, Bf, C, 0, 0, 0)

#define ACCS(F) \
    F(0,0) F(0,1) F(0,2) F(0,3) F(1,0) F(1,1) F(1,2) F(1,3) \
    F(2,0) F(2,1) F(2,2) F(2,3) F(3,0) F(3,1) F(3,2) F(3,3)

// one B fragment live at a time: column N of the accumulator
#define MFMA_COL(BUF, N) { \
    bf16x8 bb = ldB(BUF, N); \
    c0##N = MFMA_(a0, bb, c0##N); c1##N = MFMA_(a1, bb, c1##N); \
    c2##N = MFMA_(a2, bb, c2##N); c3##N = MFMA_(a3, bb, c3##N); }

#define COMPUTE(BUF) \
    a0 = ldA(BUF, 0); a1 = ldA(BUF, 1); a2 = ldA(BUF, 2); a3 = ldA(BUF, 3); \
    MFMA_COL(BUF, 0) MFMA_COL(BUF, 1) MFMA_COL(BUF, 2) MFMA_COL(BUF, 3)

#define STAGE(BUF, K0) \
    gload_lds16(aSrc + (K0),               ldsA + (BUF) * 4096); \
    gload_lds16(aSrc + 64 * K_DIM + (K0),  ldsA + (BUF) * 4096 + 2048); \
    gload_lds16(bSrc + (K0),               ldsB + (BUF) * 4096); \
    gload_lds16(bSrc + 64 * K_DIM + (K0),  ldsB + (BUF) * 4096 + 2048);

__global__ __launch_bounds__(256, 4) void gemm_fused(
    const __bf16* __restrict__ A,     // [8192][2048]
    const __bf16* __restrict__ W,     // [10240][2048]
    const float* __restrict__ bias,   // [10240]
    float* __restrict__ out,
    __bf16* __restrict__ ggi, __bf16* __restrict__ ggf,
    __bf16* __restrict__ ggib, __bf16* __restrict__ ggfb,
    __bf16* __restrict__ gpc) {
    __shared__ __bf16 As[2 * 4096];   // [2][128][32], chunk-swizzled
    __shared__ __bf16 Bs[2 * 4096];   // [2][128][32], chunk-swizzled

    // 2D-chunked per-XCD mapping (r8, verified: FETCH 0.44GB): tm band of 8 per XCD;
    // tn in 8 chunks of 10 (8tm x 10tn = 80 blocks ~ XCD concurrent capacity).
    const int bid = blockIdx.x;
    const int xcd = bid & 7;
    const int j   = bid >> 3;            // 0..639 within this XCD
    const int ch  = j / 80;              // 0..7   tn chunk (lockstep across XCDs)
    const int jj  = j % 80;              // 0..79  inside 8tm x 10tn sub-rectangle
    const int tm  = (xcd << 3) + (jj & 7);   // xcd*8 .. xcd*8+7 (A band, L2-resident)
    const int tn  = ch * 10 + (jj >> 3);     // 0..79

    const int t     = threadIdx.x;
    const int lane  = t & 63;
    const int w     = t >> 6;          // 0..3
    const int wmOff = (w >> 1) << 6;   // 0 or 64
    const int wnOff = (w & 1) << 6;    // 0 or 64
    const int lr    = lane & 15;
    const int kg    = lane >> 4;       // 0..3

    const int64_t Arow0 = (int64_t)tm * 128;
    const int64_t Wrow0 = (int64_t)tn * 128;

#define DA(M, N) f32x4 c##M##N = {0.f, 0.f, 0.f, 0.f};
    ACCS(DA)
#undef DA
    bf16x8 a0, a1, a2, a3;

    // staging: thread t covers LDS row (t>>2) (+64 for second call), physical chunk (t&3);
    // it LOADS the inverse-swizzled global chunk (t&3)^((t>>3)&3). LDS dest linear: t*16B.
    const int srcChunk = ((t & 3) ^ ((t >> 3) & 3)) << 3;  // elements
    const __bf16* aSrc = A + (Arow0 + (t >> 2)) * (int64_t)K_DIM + srcChunk;
    const __bf16* bSrc = W + (Wrow0 + (t >> 2)) * (int64_t)K_DIM + srcChunk;
    __bf16* ldsA = As + t * 8;
    __bf16* ldsB = Bs + t * 8;

    // swizzled fragment-read bases: logical chunk kg of row r at byte
    // r*64 + ((kg^((r>>1)&3))<<4). Per-lane constant; m advances 16 rows = +1024B
    // ((r>>1)&3 invariant under +16); buf advances 8192B.
    const int cs = kg ^ ((lr >> 1) & 3);
    const char* aRd = reinterpret_cast<const char*>(As) + (wmOff + lr) * 64 + (cs << 4);
    const char* bRd = reinterpret_cast<const char*>(Bs) + (wnOff + lr) * 64 + (cs << 4);

    auto ldA = [&](int buf, int m) {
        return *reinterpret_cast<const bf16x8*>(aRd + buf * 8192 + m * 1024);
    };
    auto ldB = [&](int buf, int n) {
        return *reinterpret_cast<const bf16x8*>(bRd + buf * 8192 + n * 1024);
    };

    // prologue: buf0 <- k-step 0
    STAGE(0, 0)
    __syncthreads();

#pragma unroll 1
    for (int kt = 0; kt < 64; kt += 2) {
        // step A: prefetch buf1 <- kt+1, compute buf0
        STAGE(1, (kt + 1) << 5)
        COMPUTE(0)
        __syncthreads();
        // step B: prefetch buf0 <- kt+2 (wraps dead at kt=62), compute buf1
        STAGE(0, ((kt + 2) & 63) << 5)
        COMPUTE(1)
        __syncthreads();
    }

    // ---- fused epilogue (bias folded here) ----
    const float bv0 = bias[Wrow0 + wnOff + 0 * 16 + lr];
    const float bv1 = bias[Wrow0 + wnOff + 1 * 16 + lr];
    const float bv2 = bias[Wrow0 + wnOff + 2 * 16 + lr];
    const float bv3 = bias[Wrow0 + wnOff + 3 * 16 + lr];

    const int     blk = tn >> 3;  // 128-col tile fully inside one 1024-col gate block
    const int     lg  = lane >> 4;
    const int64_t BH  = (int64_t)B_DIM * H_DIM;

    auto epi = [&](int m, int n, f32x4 a, float bv) {
        const int64_t rowb = Arow0 + wmOff + m * 16 + lg * 4;
        const int     colo = wnOff + n * 16 + lr;
        if (blk == 2) {  // go -> fp32 output (never re-read: nontemporal)
            float* dst = out + 6 * BH + (Wrow0 - 2 * (int64_t)H_DIM) + colo;
#pragma unroll
            for (int r = 0; r < 4; ++r)
                __builtin_nontemporal_store(sigmoid_f(a[r] + bv), dst + (rowb + r) * H_DIM);
        } else if (blk >= 6) {  // decay -> fp32 output ([B,4H] row-major, never re-read)
            float* dst = out + 2 * BH + (Wrow0 - 6 * (int64_t)H_DIM) + colo;
#pragma unroll
            for (int r = 0; r < 4; ++r)
                __builtin_nontemporal_store(softplus_f(a[r] + bv), dst + (rowb + r) * 4 * H_DIM);
        } else {  // gate -> bf16 workspace (re-read by combine: keep cacheable)
            __bf16* gp = (blk == 0) ? ggi : (blk == 1) ? ggf
                       : (blk == 3) ? ggib : (blk == 4) ? ggfb : gpc;
            __bf16* dst = gp + (int)(Wrow0 & 1023) + colo;
            if (blk == 5) {
#pragma unroll
                for (int r = 0; r < 4; ++r) dst[(rowb + r) * H_DIM] = (__bf16)tanh_f(a[r] + bv);
            } else {
#pragma unroll
                for (int r = 0; r < 4; ++r) dst[(rowb + r) * H_DIM] = (__bf16)sigmoid_f(a[r] + bv);
            }
        }
    };
#define EPI(M, N) epi(M, N, c##M##N, bv##N);
    ACCS(EPI)
#undef EPI
}

// ---------------- combine (cell outputs never re-read: nontemporal stores) ----------------

__global__ void combine_kernel(const __bf16* __restrict__ ggi, const __bf16* __restrict__ ggf,
                               const __bf16* __restrict__ ggib, const __bf16* __restrict__ ggfb,
                               const __bf16* __restrict__ gpc, const float* __restrict__ cp,
                               const float* __restrict__ cbp, float* __restrict__ out) {
    const int64_t BH    = (int64_t)B_DIM * H_DIM;
    const int64_t total = BH / 8;
    for (int64_t i = (int64_t)blockIdx.x * blockDim.x + threadIdx.x; i < total;
         i += (int64_t)gridDim.x * blockDim.x) {
        int64_t e = i << 3;
        bf16x8 vgi  = *reinterpret_cast<const bf16x8*>(ggi + e);
        bf16x8 vgf  = *reinterpret_cast<const bf16x8*>(ggf + e);
        bf16x8 vgib = *reinterpret_cast<const bf16x8*>(ggib + e);
        bf16x8 vgfb = *reinterpret_cast<const bf16x8*>(ggfb + e);
        bf16x8 vpc  = *reinterpret_cast<const bf16x8*>(gpc + e);
        float4 c0  = *reinterpret_cast<const float4*>(cp + e);
        float4 c1  = *reinterpret_cast<const float4*>(cp + e + 4);
        float4 cb0 = *reinterpret_cast<const float4*>(cbp + e);
        float4 cb1 = *reinterpret_cast<const float4*>(cbp + e + 4);
        float cpa[8] = {c0.x, c0.y, c0.z, c0.w, c1.x, c1.y, c1.z, c1.w};
        float cba[8] = {cb0.x, cb0.y, cb0.z, cb0.w, cb1.x, cb1.y, cb1.z, cb1.w};
        float ci[8], cbi[8];
#pragma unroll
        for (int j = 0; j < 8; ++j) {
            float pc = (float)vpc[j];
            ci[j]  = (float)vgf[j]  * cpa[j] + (float)vgi[j]  * pc;
            cbi[j] = (float)vgfb[j] * cba[j] + (float)vgib[j] * pc;
        }
        f32x4 ci0 = {ci[0], ci[1], ci[2], ci[3]};
        f32x4 ci1 = {ci[4], ci[5], ci[6], ci[7]};
        f32x4 cb0v = {cbi[0], cbi[1], cbi[2], cbi[3]};
        f32x4 cb1v = {cbi[4], cbi[5], cbi[6], cbi[7]};
        f32x4* o0 = reinterpret_cast<f32x4*>(out + e);
        __builtin_nontemporal_store(ci0, &o0[0]);
        __builtin_nontemporal_store(ci1, &o0[1]);
        f32x4* o1 = reinterpret_cast<f32x4*>(out + BH + e);
        __builtin_nontemporal_store(cb0v, &o1[0]);
        __builtin_nontemporal_store(cb1v, &o1[1]);
    }
}

// ---------------- launch ----------------

extern "C" void kernel_launch(void* const* d_in, const int* in_sizes, int n_in,
                              void* d_out, int out_size, void* d_ws, size_t ws_size,
                              hipStream_t stream) {
    const float* x   = (const float*)d_in[0];
    const float* h   = (const float*)d_in[1];
    const float* cp  = (const float*)d_in[2];
    const float* cbp = (const float*)d_in[3];
    const float* Wi  = (const float*)d_in[4];
    const float* bi  = (const float*)d_in[5];
    const float* Wf  = (const float*)d_in[6];
    const float* bfo = (const float*)d_in[7];
    const float* Wo  = (const float*)d_in[8];
    const float* bo  = (const float*)d_in[9];
    const float* Wib = (const float*)d_in[10];
    const float* bib = (const float*)d_in[11];
    const float* Wfb = (const float*)d_in[12];
    const float* bfb = (const float*)d_in[13];
    const float* Wpc = (const float*)d_in[14];
    const float* bpc = (const float*)d_in[15];
    const float* Wd  = (const float*)d_in[16];
    const float* bd  = (const float*)d_in[17];
    float* out = (float*)d_out;

    char* ws = (char*)d_ws;
    __bf16* xh   = (__bf16*)ws;
    __bf16* Wb   = (__bf16*)(ws + 33554432);
    float*  bias = (float*)(ws + 75497472);
    __bf16* ggi  = (__bf16*)(ws + 75538432);
    const size_t BH = (size_t)B_DIM * H_DIM;
    __bf16* ggf  = ggi + BH;
    __bf16* ggib = ggf + BH;
    __bf16* ggfb = ggib + BH;
    __bf16* gpc  = ggfb + BH;

    pack_xh_kernel<<<2048, 256, 0, stream>>>(x, h, xh);
    pack_W_kernel<<<2048, 256, 0, stream>>>(Wi, Wf, Wo, Wib, Wfb, Wpc, Wd, Wb);
    pack_bias_kernel<<<40, 256, 0, stream>>>(bi, bfo, bo, bib, bfb, bpc, bd, bias);

    const int grid = (B_DIM / 128) * (N_DIM / 128);  // 5120
    gemm_fused<<<grid, 256, 0, stream>>>(xh, Wb, bias, out, ggi, ggf, ggib, ggfb, gpc);

    combine_kernel<<<4096, 256, 0, stream>>>(ggi, ggf, ggib, ggfb, gpc, cp, cbp, out);
}

// Round 13
// 452.964 us; speedup vs baseline: 1.1670x; 1.1670x over previous
//
#include <hip/hip_runtime.h>
#include <hip/hip_bf16.h>
#include <cstdint>
#include <cmath>

#define B_DIM 8192
#define H_DIM 1024
#define K_DIM 2048   // 2H
#define N_DIM 10240  // 10H

typedef __bf16 bf16x8 __attribute__((ext_vector_type(8)));
typedef float  f32x4  __attribute__((ext_vector_type(4)));

static __device__ __forceinline__ float sigmoid_f(float z) {
    return 1.0f / (1.0f + __expf(-z));
}
static __device__ __forceinline__ float tanh_f(float z) {
    return 1.0f - 2.0f / (1.0f + __expf(2.0f * z));
}
static __device__ __forceinline__ float softplus_f(float z) {
    return fmaxf(z, 0.0f) + log1pf(__expf(-fabsf(z)));
}

static __device__ __forceinline__ void store_bf16x8(__bf16* p, float4 v0, float4 v1) {
    alignas(16) __bf16 t[8] = {(__bf16)v0.x, (__bf16)v0.y, (__bf16)v0.z, (__bf16)v0.w,
                               (__bf16)v1.x, (__bf16)v1.y, (__bf16)v1.z, (__bf16)v1.w};
    *reinterpret_cast<uint4*>(p) = *reinterpret_cast<const uint4*>(t);
}

static __device__ __forceinline__ void gload_lds16(const void* g, void* l) {
    auto* gp = reinterpret_cast<__attribute__((address_space(1))) unsigned int*>(
        reinterpret_cast<uintptr_t>(g));
    auto* lp = reinterpret_cast<__attribute__((address_space(3))) unsigned int*>(
        reinterpret_cast<uintptr_t>(l));
    __builtin_amdgcn_global_load_lds(gp, lp, 16, 0, 0);
}

// ---------------- fused pack kernel: one launch for xh + W + bias ----------------
// blocks [0,1024): xh pack (f32 x,h -> bf16 [B,2H]); [1024,3040): W pack (7 mats -> [10H,2H]);
// [3040,3080): bias. 8 bf16 per thread-iter, 16B stores.

#define XH_BLOCKS 1024
#define W_BLOCKS  2016
#define PK_GRID   (XH_BLOCKS + W_BLOCKS + 40)

__global__ void pack_all_kernel(const float* __restrict__ x, const float* __restrict__ h,
                                const float* __restrict__ w0, const float* __restrict__ w1,
                                const float* __restrict__ w2, const float* __restrict__ w3,
                                const float* __restrict__ w4, const float* __restrict__ w5,
                                const float* __restrict__ wd,
                                const float* __restrict__ b0, const float* __restrict__ b1,
                                const float* __restrict__ b2, const float* __restrict__ b3,
                                const float* __restrict__ b4, const float* __restrict__ b5,
                                const float* __restrict__ bd,
                                __bf16* __restrict__ xh, __bf16* __restrict__ Wb,
                                float* __restrict__ bias) {
    const int bb = blockIdx.x;
    if (bb < XH_BLOCKS) {
        // xh: 16.78M elems, 8 per iter
        const int64_t total = (int64_t)B_DIM * K_DIM / 8;
        const int64_t stride = (int64_t)XH_BLOCKS * blockDim.x;
        for (int64_t i = (int64_t)bb * blockDim.x + threadIdx.x; i < total; i += stride) {
            int64_t e = i << 3;
            int64_t b = e >> 11;
            int     c = (int)(e & 2047);   // 8-aligned; chunk never crosses x/h boundary
            const float* src = (c < H_DIM) ? (x + b * H_DIM + c) : (h + b * H_DIM + (c - H_DIM));
            float4 v0 = *reinterpret_cast<const float4*>(src);
            float4 v1 = *reinterpret_cast<const float4*>(src + 4);
            store_bf16x8(xh + e, v0, v1);
        }
    } else if (bb < XH_BLOCKS + W_BLOCKS) {
        // W: 20.97M elems, 8 per iter
        const int64_t total = (int64_t)N_DIM * K_DIM / 8;
        const int64_t stride = (int64_t)W_BLOCKS * blockDim.x;
        for (int64_t i = (int64_t)(bb - XH_BLOCKS) * blockDim.x + threadIdx.x; i < total;
             i += stride) {
            int64_t e   = i << 3;
            int     blk = (int)(e >> 21);
            const float* src;
            int64_t off;
            if (blk < 6) {
                src = (blk == 0) ? w0 : (blk == 1) ? w1 : (blk == 2) ? w2
                    : (blk == 3) ? w3 : (blk == 4) ? w4 : w5;
                off = e - ((int64_t)blk << 21);
            } else {
                src = wd;
                off = e - ((int64_t)6 << 21);
            }
            float4 v0 = *reinterpret_cast<const float4*>(src + off);
            float4 v1 = *reinterpret_cast<const float4*>(src + off + 4);
            store_bf16x8(Wb + e, v0, v1);
        }
    } else {
        int i = (bb - XH_BLOCKS - W_BLOCKS) * blockDim.x + threadIdx.x;
        if (i >= N_DIM) return;
        int blk = i >> 10;
        float v;
        if (blk < 6) {
            const float* s = (blk == 0) ? b0 : (blk == 1) ? b1 : (blk == 2) ? b2
                           : (blk == 3) ? b3 : (blk == 4) ? b4 : b5;
            v = s[i - (blk << 10)];
        } else {
            v = bd[i - (6 << 10)];
        }
        bias[i] = v;
    }
}

// ---------------- GEMM: r8 verbatim (session best, 457us) ----------------
// 128x128 tile, BK=64, 4 waves, single-buffer 32KB LDS, XOR chunk swizzle (conflicts 0),
// global_load_lds width-16, ~4 blocks/CU inter-block overlap, 2D-chunked XCD map
// (FETCH 0.44GB). r9-r12 established every axis (LDS-BW, bytes/FLOP, occupancy, dbuf
// pipelining) is null-to-negative from here: this is the m97-family operating point.

#define MFMA_(Af, Bf, C) __builtin_amdgcn_mfma_f32_16x16x32_bf16(Af, Bf, C, 0, 0, 0)

#define ACCS(F) \
    F(0,0) F(0,1) F(0,2) F(0,3) F(1,0) F(1,1) F(1,2) F(1,3) \
    F(2,0) F(2,1) F(2,2) F(2,3) F(3,0) F(3,1) F(3,2) F(3,3)

#define READF(KH) \
    a0 = ldA(0, KH); a1 = ldA(1, KH); a2 = ldA(2, KH); a3 = ldA(3, KH); \
    b0 = ldB(0, KH); b1 = ldB(1, KH); b2 = ldB(2, KH); b3 = ldB(3, KH);

#define MFMA_ALL \
    c00 = MFMA_(a0, b0, c00); c01 = MFMA_(a0, b1, c01); \
    c02 = MFMA_(a0, b2, c02); c03 = MFMA_(a0, b3, c03); \
    c10 = MFMA_(a1, b0, c10); c11 = MFMA_(a1, b1, c11); \
    c12 = MFMA_(a1, b2, c12); c13 = MFMA_(a1, b3, c13); \
    c20 = MFMA_(a2, b0, c20); c21 = MFMA_(a2, b1, c21); \
    c22 = MFMA_(a2, b2, c22); c23 = MFMA_(a2, b3, c23); \
    c30 = MFMA_(a3, b0, c30); c31 = MFMA_(a3, b1, c31); \
    c32 = MFMA_(a3, b2, c32); c33 = MFMA_(a3, b3, c33);

__global__ __launch_bounds__(256, 3) void gemm_fused(
    const __bf16* __restrict__ A,     // [8192][2048]
    const __bf16* __restrict__ W,     // [10240][2048]
    const float* __restrict__ bias,   // [10240]
    float* __restrict__ out,
    __bf16* __restrict__ ggi, __bf16* __restrict__ ggf,
    __bf16* __restrict__ ggib, __bf16* __restrict__ ggfb,
    __bf16* __restrict__ gpc) {
    __shared__ __bf16 As[8192];   // [128][64], chunk-swizzled
    __shared__ __bf16 Bs[8192];   // [128][64], chunk-swizzled

    // 2D-chunked per-XCD mapping: tm band of 8 per XCD; tn in 8 chunks of 10.
    const int bid = blockIdx.x;
    const int xcd = bid & 7;
    const int j   = bid >> 3;            // 0..639 within this XCD
    const int ch  = j / 80;              // 0..7   tn chunk (lockstep across XCDs)
    const int jj  = j % 80;              // 0..79  inside 8tm x 10tn sub-rectangle
    const int tm  = (xcd << 3) + (jj & 7);   // xcd*8 .. xcd*8+7 (A band, L2-resident)
    const int tn  = ch * 10 + (jj >> 3);     // 0..79

    const int t     = threadIdx.x;
    const int lane  = t & 63;
    const int w     = t >> 6;          // 0..3
    const int wmOff = (w >> 1) << 6;   // 0 or 64
    const int wnOff = (w & 1) << 6;    // 0 or 64
    const int lr    = lane & 15;
    const int kg    = lane >> 4;       // 0..3

    const int64_t Arow0 = (int64_t)tm * 128;
    const int64_t Wrow0 = (int64_t)tn * 128;

#define DA(M, N) f32x4 c##M##N = {0.f, 0.f, 0.f, 0.f};
    ACCS(DA)
#undef DA
    bf16x8 a0, a1, a2, a3, b0, b1, b2, b3;

    // staging: thread t covers LDS row (t>>3), physical chunk (t&7); it must LOAD the
    // inverse-swizzled global chunk (t&7)^((t>>3)&7). LDS dest linear: base + t*16B.
    const int srcChunk = ((t & 7) ^ ((t >> 3) & 7)) << 3;  // elements
    const __bf16* aSrc = A + (Arow0 + (t >> 3)) * (int64_t)K_DIM + srcChunk;
    const __bf16* bSrc = W + (Wrow0 + (t >> 3)) * (int64_t)K_DIM + srcChunk;
    __bf16* ldsA = As + t * 8;
    __bf16* ldsB = Bs + t * 8;

    // swizzled fragment-read bases: logical chunk c=kg+4*kh of row r lives at byte
    // r*128 + ((c^(r&7))<<4). kh=1 flips chunk bit2 -> base with ca^4. m: +2048B.
    const int xr  = lr & 7;
    const int ca  = kg ^ xr;                 // logical chunk for kh=0
    const char* aRd0 = reinterpret_cast<const char*>(As) + (wmOff + lr) * 128 + (ca << 4);
    const char* aRd1 = reinterpret_cast<const char*>(As) + (wmOff + lr) * 128 + ((ca ^ 4) << 4);
    const char* bRd0 = reinterpret_cast<const char*>(Bs) + (wnOff + lr) * 128 + (ca << 4);
    const char* bRd1 = reinterpret_cast<const char*>(Bs) + (wnOff + lr) * 128 + ((ca ^ 4) << 4);

    auto ldA = [&](int m, int kh) {
        return *reinterpret_cast<const bf16x8*>((kh ? aRd1 : aRd0) + m * 2048);
    };
    auto ldB = [&](int n, int kh) {
        return *reinterpret_cast<const bf16x8*>((kh ? bRd1 : bRd0) + n * 2048);
    };

#pragma unroll 1
    for (int kt = 0; kt < 32; ++kt) {
        const int k0 = kt << 6;
        __syncthreads();   // everyone done reading previous tile
        gload_lds16(aSrc + 0 * (32 * K_DIM) + k0, ldsA + 0 * 2048);
        gload_lds16(aSrc + 1 * (32 * K_DIM) + k0, ldsA + 1 * 2048);
        gload_lds16(aSrc + 2 * (32 * K_DIM) + k0, ldsA + 2 * 2048);
        gload_lds16(aSrc + 3 * (32 * K_DIM) + k0, ldsA + 3 * 2048);
        gload_lds16(bSrc + 0 * (32 * K_DIM) + k0, ldsB + 0 * 2048);
        gload_lds16(bSrc + 1 * (32 * K_DIM) + k0, ldsB + 1 * 2048);
        gload_lds16(bSrc + 2 * (32 * K_DIM) + k0, ldsB + 2 * 2048);
        gload_lds16(bSrc + 3 * (32 * K_DIM) + k0, ldsB + 3 * 2048);
        __syncthreads();   // compiler drains vmcnt before barrier: tile landed
        READF(0)
        MFMA_ALL
        READF(1)
        MFMA_ALL
    }
    __syncthreads();

    // ---- fused epilogue (bias folded here) ----
    const float bv0 = bias[Wrow0 + wnOff + 0 * 16 + lr];
    const float bv1 = bias[Wrow0 + wnOff + 1 * 16 + lr];
    const float bv2 = bias[Wrow0 + wnOff + 2 * 16 + lr];
    const float bv3 = bias[Wrow0 + wnOff + 3 * 16 + lr];

    const int     blk = tn >> 3;  // 128-col tile fully inside one 1024-col gate block
    const int     lg  = lane >> 4;
    const int64_t BH  = (int64_t)B_DIM * H_DIM;

    auto epi = [&](int m, int n, f32x4 a, float bv) {
        const int64_t rowb = Arow0 + wmOff + m * 16 + lg * 4;
        const int     colo = wnOff + n * 16 + lr;
        if (blk == 2) {  // go -> fp32 output (never re-read: nontemporal)
            float* dst = out + 6 * BH + (Wrow0 - 2 * (int64_t)H_DIM) + colo;
#pragma unroll
            for (int r = 0; r < 4; ++r)
                __builtin_nontemporal_store(sigmoid_f(a[r] + bv), dst + (rowb + r) * H_DIM);
        } else if (blk >= 6) {  // decay -> fp32 output ([B,4H] row-major, never re-read)
            float* dst = out + 2 * BH + (Wrow0 - 6 * (int64_t)H_DIM) + colo;
#pragma unroll
            for (int r = 0; r < 4; ++r)
                __builtin_nontemporal_store(softplus_f(a[r] + bv), dst + (rowb + r) * 4 * H_DIM);
        } else {  // gate -> bf16 workspace (re-read by combine: keep cacheable)
            __bf16* gp = (blk == 0) ? ggi : (blk == 1) ? ggf
                       : (blk == 3) ? ggib : (blk == 4) ? ggfb : gpc;
            __bf16* dst = gp + (int)(Wrow0 & 1023) + colo;
            if (blk == 5) {
#pragma unroll
                for (int r = 0; r < 4; ++r) dst[(rowb + r) * H_DIM] = (__bf16)tanh_f(a[r] + bv);
            } else {
#pragma unroll
                for (int r = 0; r < 4; ++r) dst[(rowb + r) * H_DIM] = (__bf16)sigmoid_f(a[r] + bv);
            }
        }
    };
#define EPI(M, N) epi(M, N, c##M##N, bv##N);
    ACCS(EPI)
#undef EPI
}

// ---------------- combine (cell outputs never re-read: nontemporal stores) ----------------

__global__ void combine_kernel(const __bf16* __restrict__ ggi, const __bf16* __restrict__ ggf,
                               const __bf16* __restrict__ ggib, const __bf16* __restrict__ ggfb,
                               const __bf16* __restrict__ gpc, const float* __restrict__ cp,
                               const float* __restrict__ cbp, float* __restrict__ out) {
    const int64_t BH    = (int64_t)B_DIM * H_DIM;
    const int64_t total = BH / 8;
    for (int64_t i = (int64_t)blockIdx.x * blockDim.x + threadIdx.x; i < total;
         i += (int64_t)gridDim.x * blockDim.x) {
        int64_t e = i << 3;
        bf16x8 vgi  = *reinterpret_cast<const bf16x8*>(ggi + e);
        bf16x8 vgf  = *reinterpret_cast<const bf16x8*>(ggf + e);
        bf16x8 vgib = *reinterpret_cast<const bf16x8*>(ggib + e);
        bf16x8 vgfb = *reinterpret_cast<const bf16x8*>(ggfb + e);
        bf16x8 vpc  = *reinterpret_cast<const bf16x8*>(gpc + e);
        float4 c0  = *reinterpret_cast<const float4*>(cp + e);
        float4 c1  = *reinterpret_cast<const float4*>(cp + e + 4);
        float4 cb0 = *reinterpret_cast<const float4*>(cbp + e);
        float4 cb1 = *reinterpret_cast<const float4*>(cbp + e + 4);
        float cpa[8] = {c0.x, c0.y, c0.z, c0.w, c1.x, c1.y, c1.z, c1.w};
        float cba[8] = {cb0.x, cb0.y, cb0.z, cb0.w, cb1.x, cb1.y, cb1.z, cb1.w};
        float ci[8], cbi[8];
#pragma unroll
        for (int j = 0; j < 8; ++j) {
            float pc = (float)vpc[j];
            ci[j]  = (float)vgf[j]  * cpa[j] + (float)vgi[j]  * pc;
            cbi[j] = (float)vgfb[j] * cba[j] + (float)vgib[j] * pc;
        }
        f32x4 ci0 = {ci[0], ci[1], ci[2], ci[3]};
        f32x4 ci1 = {ci[4], ci[5], ci[6], ci[7]};
        f32x4 cb0v = {cbi[0], cbi[1], cbi[2], cbi[3]};
        f32x4 cb1v = {cbi[4], cbi[5], cbi[6], cbi[7]};
        f32x4* o0 = reinterpret_cast<f32x4*>(out + e);
        __builtin_nontemporal_store(ci0, &o0[0]);
        __builtin_nontemporal_store(ci1, &o0[1]);
        f32x4* o1 = reinterpret_cast<f32x4*>(out + BH + e);
        __builtin_nontemporal_store(cb0v, &o1[0]);
        __builtin_nontemporal_store(cb1v, &o1[1]);
    }
}

// ---------------- launch ----------------

extern "C" void kernel_launch(void* const* d_in, const int* in_sizes, int n_in,
                              void* d_out, int out_size, void* d_ws, size_t ws_size,
                              hipStream_t stream) {
    const float* x   = (const float*)d_in[0];
    const float* h   = (const float*)d_in[1];
    const float* cp  = (const float*)d_in[2];
    const float* cbp = (const float*)d_in[3];
    const float* Wi  = (const float*)d_in[4];
    const float* bi  = (const float*)d_in[5];
    const float* Wf  = (const float*)d_in[6];
    const float* bfo = (const float*)d_in[7];
    const float* Wo  = (const float*)d_in[8];
    const float* bo  = (const float*)d_in[9];
    const float* Wib = (const float*)d_in[10];
    const float* bib = (const float*)d_in[11];
    const float* Wfb = (const float*)d_in[12];
    const float* bfb = (const float*)d_in[13];
    const float* Wpc = (const float*)d_in[14];
    const float* bpc = (const float*)d_in[15];
    const float* Wd  = (const float*)d_in[16];
    const float* bd  = (const float*)d_in[17];
    float* out = (float*)d_out;

    char* ws = (char*)d_ws;
    __bf16* xh   = (__bf16*)ws;
    __bf16* Wb   = (__bf16*)(ws + 33554432);
    float*  bias = (float*)(ws + 75497472);
    __bf16* ggi  = (__bf16*)(ws + 75538432);
    const size_t BH = (size_t)B_DIM * H_DIM;
    __bf16* ggf  = ggi + BH;
    __bf16* ggib = ggf + BH;
    __bf16* ggfb = ggib + BH;
    __bf16* gpc  = ggfb + BH;

    pack_all_kernel<<<PK_GRID, 256, 0, stream>>>(x, h, Wi, Wf, Wo, Wib, Wfb, Wpc, Wd,
                                                 bi, bfo, bo, bib, bfb, bpc, bd,
                                                 xh, Wb, bias);

    const int grid = (B_DIM / 128) * (N_DIM / 128);  // 5120
    gemm_fused<<<grid, 256, 0, stream>>>(xh, Wb, bias, out, ggi, ggf, ggib, ggfb, gpc);

    combine_kernel<<<4096, 256, 0, stream>>>(ggi, ggf, ggib, ggfb, gpc, cp, cbp, out);
}